// Round 1
// baseline (64.973 us; speedup 1.0000x reference)
//
#include <hip/hip_runtime.h>
#include <hip/hip_bf16.h>

// Problem constants
#define BB     32
#define TT     64
#define NNP    128
#define HIDD   128
#define ATT    128
#define SS     (TT * NNP)     // 8192 positions per batch
#define SCC    128            // positions per chunk (block)
#define NCHUNK (SS / SCC)     // 64
#define PART_STRIDE 130       // [m, l, acc[128]]

typedef float f32x4 __attribute__((ext_vector_type(4)));
typedef short s16x8 __attribute__((ext_vector_type(8)));

__device__ inline unsigned short f2bf(float x) {
    unsigned u = __float_as_uint(x);
    u += 0x7FFFu + ((u >> 16) & 1u);   // round-to-nearest-even
    return (unsigned short)(u >> 16);
}
__device__ inline float bf2f(unsigned short h) {
    return __uint_as_float(((unsigned)h) << 16);
}
__device__ inline float fast_tanh(float x) {
    x = fminf(15.f, fmaxf(-15.f, x));
    float e2 = __expf(2.f * x);
    return (e2 - 1.f) * __builtin_amdgcn_rcpf(e2 + 1.f);
}

// ---- prep 1: Wh_w f32 -> bf16 (in workspace) ----
__global__ void prep_w_kernel(const float* __restrict__ whw,
                              unsigned short* __restrict__ wbf) {
    int i = blockIdx.x * 256 + threadIdx.x;   // 16384 total
    wbf[i] = f2bf(whw[i]);
}

// ---- prep 2: bias2[b][a] = Wh_b[a] + Wx_b[a] + cur_h[b,:].Wx_w[a,:] ----
__global__ void prep_bias_kernel(const float* __restrict__ cur,
                                 const float* __restrict__ wxw,
                                 const float* __restrict__ wxb,
                                 const float* __restrict__ whb,
                                 float* __restrict__ bias2) {
    __shared__ float sc[HIDD];
    int b = blockIdx.x, a = threadIdx.x;   // 128 threads
    sc[a] = cur[b * HIDD + a];
    __syncthreads();
    float d = 0.f;
#pragma unroll 8
    for (int h = 0; h < HIDD; ++h) d += sc[h] * wxw[a * HIDD + h];
    bias2[b * ATT + a] = d + wxb[a] + whb[a];
}

// ---- main: per (b, chunk): proj GEMM (bf16 MFMA) + tanh + v-dot +
//      chunk-local online-softmax partials (m, l, sum e*h) ----
__global__ __launch_bounds__(256) void attn_main_kernel(
    const float* __restrict__ hist,
    const unsigned short* __restrict__ wbf,
    const float* __restrict__ bias2,
    const float* __restrict__ vw,
    float* __restrict__ partials)
{
    __shared__ __align__(16) unsigned short sH[SCC * HIDD];  // 32 KB, swizzled
    __shared__ __align__(16) unsigned short sW[ATT * HIDD];  // 32 KB, swizzled
    __shared__ float sScore[SCC];
    __shared__ float sBias[ATT];
    __shared__ float sV[ATT];
    __shared__ float sRed[8];
    __shared__ float sAcc[4 * HIDD];

    const int tid  = threadIdx.x;
    const int bid  = blockIdx.x;
    const int b    = bid >> 6;      // NCHUNK = 64
    const int chunk = bid & 63;
    const int lane = tid & 63;
    const int wid  = tid >> 6;
    const int l15  = lane & 15;
    const int lg   = lane >> 4;

    // stage Wh_w (bf16) -> LDS with XOR swizzle (u16 units: idx ^= (row&7)<<3)
#pragma unroll
    for (int i = 0; i < 8; ++i) {
        int u = i * 256 + tid;          // 16B unit, 0..2047
        int e = u * 8;                  // u16 index
        int row = e >> 7;
        s16x8 v = *(const s16x8*)(wbf + e);
        *(s16x8*)&sW[e ^ ((row & 7) << 3)] = v;
    }
    // stage history chunk f32 -> bf16 -> LDS, swizzled
    const float* hb = hist + ((size_t)b * SS + (size_t)chunk * SCC) * HIDD;
#pragma unroll
    for (int i = 0; i < 16; ++i) {
        int g = i * 256 + tid;          // float4 index, 0..4095
        int f = g * 4;
        int row = f >> 7;
        int col = f & 127;
        float4 v = *(const float4*)(hb + f);
        ushort4 o;
        o.x = f2bf(v.x); o.y = f2bf(v.y); o.z = f2bf(v.z); o.w = f2bf(v.w);
        *(ushort4*)&sH[(row * HIDD + col) ^ ((row & 7) << 3)] = o;
    }
    if (tid < ATT) {
        sBias[tid] = bias2[b * ATT + tid];
        sV[tid]    = vw[tid];
    }
    __syncthreads();

    // ---- projection GEMM: D[s,a] = hist[s,:] . Wh_w[a,:] via 16x16x32 MFMA ----
    // A frag: row = lane&15 (s), k = (lane>>4)*8 + i  -> contiguous 8 bf16
    // B frag: col = lane&15 (a == row of Wh_w), same k pattern
    // D: col = lane&15 (a), row = (lane>>4)*4 + r (s)
    s16x8 afrag[2][4];
#pragma unroll
    for (int st = 0; st < 2; ++st) {
        int srow = (wid * 2 + st) * 16 + l15;
#pragma unroll
        for (int kk = 0; kk < 4; ++kk) {
            int idx = (srow * HIDD + kk * 32 + lg * 8) ^ ((srow & 7) << 3);
            afrag[st][kk] = *(const s16x8*)&sH[idx];
        }
    }
    float p[2][4] = {{0.f,0.f,0.f,0.f},{0.f,0.f,0.f,0.f}};
#pragma unroll
    for (int at = 0; at < 8; ++at) {
        s16x8 bfrag[4];
        int arow = at * 16 + l15;
#pragma unroll
        for (int kk = 0; kk < 4; ++kk) {
            int idx = (arow * HIDD + kk * 32 + lg * 8) ^ ((arow & 7) << 3);
            bfrag[kk] = *(const s16x8*)&sW[idx];
        }
        float bia = sBias[at * 16 + l15];
        float vv  = sV[at * 16 + l15];
#pragma unroll
        for (int st = 0; st < 2; ++st) {
            f32x4 acc = {0.f, 0.f, 0.f, 0.f};
#pragma unroll
            for (int kk = 0; kk < 4; ++kk)
                acc = __builtin_amdgcn_mfma_f32_16x16x32_bf16(afrag[st][kk], bfrag[kk], acc, 0, 0, 0);
#pragma unroll
            for (int r = 0; r < 4; ++r)
                p[st][r] += vv * fast_tanh(acc[r] + bia);
        }
    }
    // reduce over the 16 a-columns held across lanes (same s within 16-lane group)
#pragma unroll
    for (int m = 1; m <= 8; m <<= 1) {
#pragma unroll
        for (int st = 0; st < 2; ++st)
#pragma unroll
            for (int r = 0; r < 4; ++r)
                p[st][r] += __shfl_xor(p[st][r], m, 64);
    }
    if (l15 == 0) {
#pragma unroll
        for (int st = 0; st < 2; ++st)
#pragma unroll
            for (int r = 0; r < 4; ++r)
                sScore[(wid * 2 + st) * 16 + lg * 4 + r] = p[st][r];
    }
    __syncthreads();

    // ---- chunk-local softmax stats ----
    float scv = sScore[tid & 127];
    float mx = scv;
#pragma unroll
    for (int m = 1; m < 64; m <<= 1) mx = fmaxf(mx, __shfl_xor(mx, m, 64));
    if (lane == 0) sRed[wid] = mx;
    __syncthreads();
    mx = fmaxf(fmaxf(sRed[0], sRed[1]), fmaxf(sRed[2], sRed[3]));
    float ev = (tid < 128) ? __expf(scv - mx) : 0.f;
    float es = ev;
#pragma unroll
    for (int m = 1; m < 64; m <<= 1) es += __shfl_xor(es, m, 64);
    if (lane == 0) sRed[4 + wid] = es;
    __syncthreads();
    float lsum = sRed[4] + sRed[5] + sRed[6] + sRed[7];
    if (tid < 128) sScore[tid] = ev;   // all reads of old sScore completed (barrier above)
    __syncthreads();

    // ---- weighted accumulation: acc[h] = sum_s e[s] * hist[s][h] ----
    {
        int hp = tid & 63;     // h pair: h = 2*hp, 2*hp+1
        int sg = tid >> 6;     // s quarter
        float a0 = 0.f, a1 = 0.f;
#pragma unroll 4
        for (int s = sg * 32; s < sg * 32 + 32; ++s) {
            float w = sScore[s];
            int idx = (s * HIDD + hp * 2) ^ ((s & 7) << 3);
            ushort2 hv = *(const ushort2*)&sH[idx];
            a0 += w * bf2f(hv.x);
            a1 += w * bf2f(hv.y);
        }
        sAcc[sg * HIDD + hp * 2]     = a0;
        sAcc[sg * HIDD + hp * 2 + 1] = a1;
    }
    __syncthreads();
    float* part = partials + (size_t)(b * NCHUNK + chunk) * PART_STRIDE;
    if (tid == 0) { part[0] = mx; part[1] = lsum; }
    if (tid < 128)
        part[2 + tid] = sAcc[tid] + sAcc[128 + tid] + sAcc[256 + tid] + sAcc[384 + tid];
}

// ---- combine: merge chunk partials, add cur_h ----
__global__ void attn_combine_kernel(const float* __restrict__ cur,
                                    const float* __restrict__ partials,
                                    float* __restrict__ out)
{
    int b = blockIdx.x, h = threadIdx.x;   // 128 threads
    const float* pb = partials + (size_t)b * NCHUNK * PART_STRIDE;
    float M = -INFINITY;
    for (int c = 0; c < NCHUNK; ++c) M = fmaxf(M, pb[c * PART_STRIDE]);
    float num = 0.f, den = 0.f;
    for (int c = 0; c < NCHUNK; ++c) {
        float scale = __expf(pb[c * PART_STRIDE] - M);
        den += pb[c * PART_STRIDE + 1] * scale;
        num += pb[c * PART_STRIDE + 2 + h] * scale;
    }
    out[b * HIDD + h] = cur[b * HIDD + h] + num / den;
}

extern "C" void kernel_launch(void* const* d_in, const int* in_sizes, int n_in,
                              void* d_out, int out_size, void* d_ws, size_t ws_size,
                              hipStream_t stream) {
    const float* cur  = (const float*)d_in[0];
    const float* hist = (const float*)d_in[1];
    const float* wxw  = (const float*)d_in[2];
    const float* wxb  = (const float*)d_in[3];
    const float* whw  = (const float*)d_in[4];
    const float* whb  = (const float*)d_in[5];
    const float* vw   = (const float*)d_in[6];
    float* out = (float*)d_out;

    // workspace layout: [wbf 32KB][bias2 16KB][partials 32*64*130 f32]
    unsigned short* wbf = (unsigned short*)d_ws;
    float* bias2    = (float*)((char*)d_ws + 32768);
    float* partials = (float*)((char*)d_ws + 32768 + 16384);

    prep_w_kernel<<<(ATT * HIDD) / 256, 256, 0, stream>>>(whw, wbf);
    prep_bias_kernel<<<BB, ATT, 0, stream>>>(cur, wxw, wxb, whb, bias2);
    attn_main_kernel<<<BB * NCHUNK, 256, 0, stream>>>(hist, wbf, bias2, vw, partials);
    attn_combine_kernel<<<BB, HIDD, 0, stream>>>(cur, partials, out);
}

// Round 2
// 57.787 us; speedup vs baseline: 1.1244x; 1.1244x over previous
//
#include <hip/hip_runtime.h>
#include <hip/hip_bf16.h>

// Problem constants
#define BB     32
#define TT     64
#define NNP    128
#define HIDD   128
#define ATT    128
#define SS     (TT * NNP)     // 8192 positions per batch
#define SCC    128            // positions per chunk (block)
#define NCHUNK (SS / SCC)     // 64
#define PART_STRIDE 130       // [m, l, acc[128]]

typedef float f32x4 __attribute__((ext_vector_type(4)));
typedef short s16x8 __attribute__((ext_vector_type(8)));

__device__ inline unsigned short f2bf(float x) {
    unsigned u = __float_as_uint(x);
    u += 0x7FFFu + ((u >> 16) & 1u);   // round-to-nearest-even
    return (unsigned short)(u >> 16);
}
__device__ inline float bf2f(unsigned short h) {
    return __uint_as_float(((unsigned)h) << 16);
}
__device__ inline float fast_tanh(float x) {
    x = fminf(15.f, fmaxf(-15.f, x));
    float e2 = __expf(2.f * x);
    return (e2 - 1.f) * __builtin_amdgcn_rcpf(e2 + 1.f);
}

// ---- prep (merged): blocks 0..63 -> Wh_w f32->bf16; blocks 64..95 -> bias2 ----
__global__ void prep_kernel(const float* __restrict__ whw,
                            unsigned short* __restrict__ wbf,
                            const float* __restrict__ cur,
                            const float* __restrict__ wxw,
                            const float* __restrict__ wxb,
                            const float* __restrict__ whb,
                            float* __restrict__ bias2) {
    if (blockIdx.x < 64) {
        int i = blockIdx.x * 256 + threadIdx.x;   // 16384 total
        wbf[i] = f2bf(whw[i]);
    } else {
        __shared__ float sc[HIDD];
        int b = blockIdx.x - 64;
        int a = threadIdx.x;
        if (a < HIDD) sc[a] = cur[b * HIDD + a];
        __syncthreads();
        if (a < ATT) {
            float d = 0.f;
#pragma unroll 8
            for (int h = 0; h < HIDD; ++h) d += sc[h] * wxw[a * HIDD + h];
            bias2[b * ATT + a] = d + wxb[a] + whb[a];
        }
    }
}

// ---- main: per (b, chunk): proj GEMM (bf16 MFMA, weights in registers) +
//      tanh + v-dot + chunk-local online-softmax partials (m, l, sum e*h) ----
__global__ __launch_bounds__(256, 4) void attn_main_kernel(
    const float* __restrict__ hist,
    const unsigned short* __restrict__ wbf,
    const float* __restrict__ bias2,
    const float* __restrict__ vw,
    float* __restrict__ partials)
{
    __shared__ __align__(16) unsigned short sH[SCC * HIDD];  // 32 KB, swizzled
    __shared__ float sScoreP[4][SCC];                        // per-wave partial scores
    __shared__ float sScore[SCC];
    __shared__ float sRed[8];
    __shared__ float sAcc[4 * HIDD];

    const int tid  = threadIdx.x;
    const int bid  = blockIdx.x;
    const int b    = bid >> 6;      // NCHUNK = 64
    const int chunk = bid & 63;
    const int lane = tid & 63;
    const int wid  = tid >> 6;
    const int l15  = lane & 15;
    const int lg   = lane >> 4;

    // ---- stage history chunk f32 -> bf16 -> LDS, swizzled (issued first) ----
    const float* hb = hist + ((size_t)b * SS + (size_t)chunk * SCC) * HIDD;
#pragma unroll
    for (int i = 0; i < 16; ++i) {
        int g = i * 256 + tid;          // float4 index, 0..4095
        int f = g * 4;
        int row = f >> 7;
        int col = f & 127;
        float4 v = *(const float4*)(hb + f);
        ushort4 o;
        o.x = f2bf(v.x); o.y = f2bf(v.y); o.z = f2bf(v.z); o.w = f2bf(v.w);
        *(ushort4*)&sH[(row * HIDD + col) ^ ((row & 7) << 3)] = o;
    }

    // ---- weights for this wave's 2 a-tiles: registers, loaded from global (L2-hot) ----
    // B frag: a-row = (wid*2+j)*16 + l15, k = kk*32 + lg*8 .. +7
    s16x8 bfrag[2][4];
    float bia[2], vv[2];
#pragma unroll
    for (int j = 0; j < 2; ++j) {
        int a = (wid * 2 + j) * 16 + l15;
#pragma unroll
        for (int kk = 0; kk < 4; ++kk)
            bfrag[j][kk] = *(const s16x8*)(wbf + a * HIDD + kk * 32 + lg * 8);
        bia[j] = bias2[b * ATT + a];
        vv[j]  = vw[a];
    }
    __syncthreads();

    // ---- projection GEMM: each wave: all 8 s-tiles x its 2 a-tiles ----
    // A frag: s-row = st*16 + (lane&15), k = (lane>>4)*8 + i
    // D: a-col = lane&15, s-row = st*16 + (lane>>4)*4 + r
#pragma unroll
    for (int st = 0; st < 8; ++st) {
        int srow = st * 16 + l15;
        s16x8 afrag[4];
#pragma unroll
        for (int kk = 0; kk < 4; ++kk) {
            int idx = (srow * HIDD + kk * 32 + lg * 8) ^ ((srow & 7) << 3);
            afrag[kk] = *(const s16x8*)&sH[idx];
        }
        f32x4 acc0 = {0.f, 0.f, 0.f, 0.f};
        f32x4 acc1 = {0.f, 0.f, 0.f, 0.f};
#pragma unroll
        for (int kk = 0; kk < 4; ++kk) {
            acc0 = __builtin_amdgcn_mfma_f32_16x16x32_bf16(afrag[kk], bfrag[0][kk], acc0, 0, 0, 0);
            acc1 = __builtin_amdgcn_mfma_f32_16x16x32_bf16(afrag[kk], bfrag[1][kk], acc1, 0, 0, 0);
        }
        float ps[4];
#pragma unroll
        for (int r = 0; r < 4; ++r)
            ps[r] = vv[0] * fast_tanh(acc0[r] + bia[0]) + vv[1] * fast_tanh(acc1[r] + bia[1]);
        // reduce over the 16 a-lanes (same s within each 16-lane group)
#pragma unroll
        for (int m = 1; m <= 8; m <<= 1)
#pragma unroll
            for (int r = 0; r < 4; ++r)
                ps[r] += __shfl_xor(ps[r], m, 64);
        if (l15 == 0) {
#pragma unroll
            for (int r = 0; r < 4; ++r)
                sScoreP[wid][st * 16 + lg * 4 + r] = ps[r];
        }
    }
    __syncthreads();

    // ---- combine per-wave partials; chunk-local softmax stats ----
    int sidx = tid & 127;
    float scv = sScoreP[0][sidx] + sScoreP[1][sidx] + sScoreP[2][sidx] + sScoreP[3][sidx];
    float mx = scv;
#pragma unroll
    for (int m = 1; m < 64; m <<= 1) mx = fmaxf(mx, __shfl_xor(mx, m, 64));
    if (lane == 0) sRed[wid] = mx;
    __syncthreads();
    mx = fmaxf(fmaxf(sRed[0], sRed[1]), fmaxf(sRed[2], sRed[3]));
    float ev = (tid < 128) ? __expf(scv - mx) : 0.f;
    float es = ev;
#pragma unroll
    for (int m = 1; m < 64; m <<= 1) es += __shfl_xor(es, m, 64);
    if (lane == 0) sRed[4 + wid] = es;
    __syncthreads();
    float lsum = sRed[4] + sRed[5] + sRed[6] + sRed[7];
    if (tid < 128) sScore[tid] = ev;
    __syncthreads();

    // ---- weighted accumulation: acc[h] = sum_s e[s] * hist[s][h] ----
    {
        int hp = tid & 63;     // h pair: h = 2*hp, 2*hp+1
        int sg = tid >> 6;     // s quarter
        float a0 = 0.f, a1 = 0.f;
#pragma unroll 4
        for (int s = sg * 32; s < sg * 32 + 32; ++s) {
            float w = sScore[s];
            int idx = (s * HIDD + hp * 2) ^ ((s & 7) << 3);
            ushort2 hv = *(const ushort2*)&sH[idx];
            a0 += w * bf2f(hv.x);
            a1 += w * bf2f(hv.y);
        }
        sAcc[sg * HIDD + hp * 2]     = a0;
        sAcc[sg * HIDD + hp * 2 + 1] = a1;
    }
    __syncthreads();
    float* part = partials + (size_t)(b * NCHUNK + chunk) * PART_STRIDE;
    if (tid == 0) { part[0] = mx; part[1] = lsum; }
    if (tid < 128)
        part[2 + tid] = sAcc[tid] + sAcc[128 + tid] + sAcc[256 + tid] + sAcc[384 + tid];
}

// ---- combine: merge chunk partials, add cur_h ----
__global__ void attn_combine_kernel(const float* __restrict__ cur,
                                    const float* __restrict__ partials,
                                    float* __restrict__ out)
{
    int b = blockIdx.x, h = threadIdx.x;   // 128 threads
    const float* pb = partials + (size_t)b * NCHUNK * PART_STRIDE;
    float M = -INFINITY;
    for (int c = 0; c < NCHUNK; ++c) M = fmaxf(M, pb[c * PART_STRIDE]);
    float num = 0.f, den = 0.f;
    for (int c = 0; c < NCHUNK; ++c) {
        float scale = __expf(pb[c * PART_STRIDE] - M);
        den += pb[c * PART_STRIDE + 1] * scale;
        num += pb[c * PART_STRIDE + 2 + h] * scale;
    }
    out[b * HIDD + h] = cur[b * HIDD + h] + num / den;
}

extern "C" void kernel_launch(void* const* d_in, const int* in_sizes, int n_in,
                              void* d_out, int out_size, void* d_ws, size_t ws_size,
                              hipStream_t stream) {
    const float* cur  = (const float*)d_in[0];
    const float* hist = (const float*)d_in[1];
    const float* wxw  = (const float*)d_in[2];
    const float* wxb  = (const float*)d_in[3];
    const float* whw  = (const float*)d_in[4];
    const float* whb  = (const float*)d_in[5];
    const float* vw   = (const float*)d_in[6];
    float* out = (float*)d_out;

    // workspace layout: [wbf 32KB][bias2 16KB][partials 32*64*130 f32]
    unsigned short* wbf = (unsigned short*)d_ws;
    float* bias2    = (float*)((char*)d_ws + 32768);
    float* partials = (float*)((char*)d_ws + 32768 + 16384);

    prep_kernel<<<96, 256, 0, stream>>>(whw, wbf, cur, wxw, wxb, whb, bias2);
    attn_main_kernel<<<BB * NCHUNK, 256, 0, stream>>>(hist, wbf, bias2, vw, partials);
    attn_combine_kernel<<<BB, HIDD, 0, stream>>>(cur, partials, out);
}

// Round 3
// 53.167 us; speedup vs baseline: 1.2221x; 1.0869x over previous
//
#include <hip/hip_runtime.h>
#include <hip/hip_bf16.h>

// Problem constants
#define BB     32
#define TT     64
#define NNP    128
#define HIDD   128
#define ATT    128
#define SS     (TT * NNP)     // 8192 positions per batch
#define SCC    128            // positions per chunk (block)
#define NCHUNK (SS / SCC)     // 64
#define PART_STRIDE 130       // [m, l, acc[128]]

typedef float f32x4 __attribute__((ext_vector_type(4)));
typedef short s16x8 __attribute__((ext_vector_type(8)));

__device__ inline unsigned short f2bf(float x) {
    unsigned u = __float_as_uint(x);
    u += 0x7FFFu + ((u >> 16) & 1u);   // round-to-nearest-even
    return (unsigned short)(u >> 16);
}
__device__ inline float bf2f(unsigned short h) {
    return __uint_as_float(((unsigned)h) << 16);
}
__device__ inline float fast_tanh(float x) {
    x = fminf(15.f, fmaxf(-15.f, x));
    float e2 = __expf(2.f * x);
    return (e2 - 1.f) * __builtin_amdgcn_rcpf(e2 + 1.f);
}

// ---- prep (merged): blocks 0..63 -> Wh_w f32->bf16; blocks 64..95 -> bias2 ----
__global__ void prep_kernel(const float* __restrict__ whw,
                            unsigned short* __restrict__ wbf,
                            const float* __restrict__ cur,
                            const float* __restrict__ wxw,
                            const float* __restrict__ wxb,
                            const float* __restrict__ whb,
                            float* __restrict__ bias2) {
    if (blockIdx.x < 64) {
        int i = blockIdx.x * 256 + threadIdx.x;   // 16384 total
        wbf[i] = f2bf(whw[i]);
    } else {
        __shared__ float sc[HIDD];
        int b = blockIdx.x - 64;
        int a = threadIdx.x;
        if (a < HIDD) sc[a] = cur[b * HIDD + a];
        __syncthreads();
        if (a < ATT) {
            float d = 0.f;
#pragma unroll 8
            for (int h = 0; h < HIDD; ++h) d += sc[h] * wxw[a * HIDD + h];
            bias2[b * ATT + a] = d + wxb[a] + whb[a];
        }
    }
}

// ---- main: per (b, chunk). Projection via SWAPPED MFMA: D = W x H^T so the
//      v-dot over 'a' reduces IN-LANE (a lives in acc regs / a-tile loop),
//      leaving only 2 shfl_xor per s-tile. ----
__global__ __launch_bounds__(256, 4) void attn_main_kernel(
    const float* __restrict__ hist,
    const unsigned short* __restrict__ wbf,
    const float* __restrict__ bias2,
    const float* __restrict__ vw,
    float* __restrict__ partials)
{
    __shared__ __align__(16) unsigned short sH[SCC * HIDD];  // 32 KB, swizzled
    __shared__ float sScoreP[4][SCC];                        // per-wave partial scores
    __shared__ float sScore[SCC];
    __shared__ float sRed[8];
    __shared__ float sAcc[8 * HIDD];                         // 4 KB

    const int tid  = threadIdx.x;
    const int bid  = blockIdx.x;
    const int b    = bid >> 6;      // NCHUNK = 64
    const int chunk = bid & 63;
    const int lane = tid & 63;
    const int wid  = tid >> 6;
    const int l15  = lane & 15;
    const int lg   = lane >> 4;

    // ---- stage history chunk f32 -> bf16 -> LDS, swizzled (2 batches of 8) ----
    const float* hb = hist + ((size_t)b * SS + (size_t)chunk * SCC) * HIDD;
#pragma unroll
    for (int half = 0; half < 2; ++half) {
        float4 vb[8];
#pragma unroll
        for (int i = 0; i < 8; ++i)
            vb[i] = *(const float4*)(hb + ((half * 8 + i) * 256 + tid) * 4);
#pragma unroll
        for (int i = 0; i < 8; ++i) {
            int f = ((half * 8 + i) * 256 + tid) * 4;
            int row = f >> 7;
            int col = f & 127;
            ushort4 o;
            o.x = f2bf(vb[i].x); o.y = f2bf(vb[i].y);
            o.z = f2bf(vb[i].z); o.w = f2bf(vb[i].w);
            *(ushort4*)&sH[(row * HIDD + col) ^ ((row & 7) << 3)] = o;
        }
    }

    // ---- this wave's 2 a-tiles: W fragments (A operand), bias, v in registers ----
    // A frag (m = a): row = a-tile*16 + l15, k = kk*32 + lg*8 .. +7
    s16x8 wfrag[2][4];
    float bia[2][4], vv[2][4];
#pragma unroll
    for (int j = 0; j < 2; ++j) {
        int arow = (wid * 2 + j) * 16 + l15;
#pragma unroll
        for (int kk = 0; kk < 4; ++kk)
            wfrag[j][kk] = *(const s16x8*)(wbf + arow * HIDD + kk * 32 + lg * 8);
#pragma unroll
        for (int r = 0; r < 4; ++r) {
            int a = (wid * 2 + j) * 16 + lg * 4 + r;   // D-row index for reg r
            bia[j][r] = bias2[b * ATT + a];
            vv[j][r]  = vw[a];
        }
    }
    __syncthreads();

    // ---- projection: for each s-tile, D[a][s] = W . H^T; v-dot in-lane ----
    // B frag (n = s): col = l15 = s, k = kk*32 + lg*8 + i -> H[s][k] (same LDS
    // read pattern as before). D: col = l15 = s, row = lg*4 + r = a.
#pragma unroll
    for (int st = 0; st < 8; ++st) {
        int srow = st * 16 + l15;
        s16x8 hfrag[4];
#pragma unroll
        for (int kk = 0; kk < 4; ++kk) {
            int idx = (srow * HIDD + kk * 32 + lg * 8) ^ ((srow & 7) << 3);
            hfrag[kk] = *(const s16x8*)&sH[idx];
        }
        f32x4 acc0 = {0.f, 0.f, 0.f, 0.f};
        f32x4 acc1 = {0.f, 0.f, 0.f, 0.f};
#pragma unroll
        for (int kk = 0; kk < 4; ++kk) {
            acc0 = __builtin_amdgcn_mfma_f32_16x16x32_bf16(wfrag[0][kk], hfrag[kk], acc0, 0, 0, 0);
            acc1 = __builtin_amdgcn_mfma_f32_16x16x32_bf16(wfrag[1][kk], hfrag[kk], acc1, 0, 0, 0);
        }
        float p = 0.f;
#pragma unroll
        for (int r = 0; r < 4; ++r)
            p += vv[0][r] * fast_tanh(acc0[r] + bia[0][r])
               + vv[1][r] * fast_tanh(acc1[r] + bia[1][r]);
        // combine the 4 lane-groups (different a-rows, same s = l15)
        p += __shfl_xor(p, 16, 64);
        p += __shfl_xor(p, 32, 64);
        if (lg == 0) sScoreP[wid][st * 16 + l15] = p;
    }
    __syncthreads();

    // ---- combine per-wave partials; chunk-local softmax stats ----
    int sidx = tid & 127;
    float scv = sScoreP[0][sidx] + sScoreP[1][sidx] + sScoreP[2][sidx] + sScoreP[3][sidx];
    float mx = scv;
#pragma unroll
    for (int m = 1; m < 64; m <<= 1) mx = fmaxf(mx, __shfl_xor(mx, m, 64));
    if (lane == 0) sRed[wid] = mx;
    __syncthreads();
    mx = fmaxf(fmaxf(sRed[0], sRed[1]), fmaxf(sRed[2], sRed[3]));
    float ev = (tid < 128) ? __expf(scv - mx) : 0.f;
    float es = ev;
#pragma unroll
    for (int m = 1; m < 64; m <<= 1) es += __shfl_xor(es, m, 64);
    if (lane == 0) sRed[4 + wid] = es;
    __syncthreads();
    float lsum = sRed[4] + sRed[5] + sRed[6] + sRed[7];
    if (tid < 128) sScore[tid] = ev;
    __syncthreads();

    // ---- weighted accumulation: acc[h] = sum_s e[s] * hist[s][h] (b64 reads) ----
    {
        int hq = tid & 31;     // h quad: h = hq*4 .. hq*4+3
        int sg = tid >> 5;     // 8 s-groups of 16
        float a0 = 0.f, a1 = 0.f, a2 = 0.f, a3 = 0.f;
#pragma unroll 8
        for (int s5 = 0; s5 < 16; ++s5) {
            int s = sg * 16 + s5;
            float w = sScore[s];
            int idx = (s * HIDD + hq * 4) ^ ((s & 7) << 3);
            ushort4 hv = *(const ushort4*)&sH[idx];
            a0 += w * bf2f(hv.x);
            a1 += w * bf2f(hv.y);
            a2 += w * bf2f(hv.z);
            a3 += w * bf2f(hv.w);
        }
        float4 o; o.x = a0; o.y = a1; o.z = a2; o.w = a3;
        *(float4*)&sAcc[sg * HIDD + hq * 4] = o;
    }
    __syncthreads();
    float* part = partials + (size_t)(b * NCHUNK + chunk) * PART_STRIDE;
    if (tid == 0) { part[0] = mx; part[1] = lsum; }
    if (tid < 128) {
        float s = 0.f;
#pragma unroll
        for (int g = 0; g < 8; ++g) s += sAcc[g * HIDD + tid];
        part[2 + tid] = s;
    }
}

// ---- combine: merge chunk partials, add cur_h ----
__global__ void attn_combine_kernel(const float* __restrict__ cur,
                                    const float* __restrict__ partials,
                                    float* __restrict__ out)
{
    int b = blockIdx.x, h = threadIdx.x;   // 128 threads
    const float* pb = partials + (size_t)b * NCHUNK * PART_STRIDE;
    float M = -INFINITY;
    for (int c = 0; c < NCHUNK; ++c) M = fmaxf(M, pb[c * PART_STRIDE]);
    float num = 0.f, den = 0.f;
    for (int c = 0; c < NCHUNK; ++c) {
        float scale = __expf(pb[c * PART_STRIDE] - M);
        den += pb[c * PART_STRIDE + 1] * scale;
        num += pb[c * PART_STRIDE + 2 + h] * scale;
    }
    out[b * HIDD + h] = cur[b * HIDD + h] + num / den;
}

extern "C" void kernel_launch(void* const* d_in, const int* in_sizes, int n_in,
                              void* d_out, int out_size, void* d_ws, size_t ws_size,
                              hipStream_t stream) {
    const float* cur  = (const float*)d_in[0];
    const float* hist = (const float*)d_in[1];
    const float* wxw  = (const float*)d_in[2];
    const float* wxb  = (const float*)d_in[3];
    const float* whw  = (const float*)d_in[4];
    const float* whb  = (const float*)d_in[5];
    const float* vw   = (const float*)d_in[6];
    float* out = (float*)d_out;

    // workspace layout: [wbf 32KB][bias2 16KB][partials 32*64*130 f32]
    unsigned short* wbf = (unsigned short*)d_ws;
    float* bias2    = (float*)((char*)d_ws + 32768);
    float* partials = (float*)((char*)d_ws + 32768 + 16384);

    prep_kernel<<<96, 256, 0, stream>>>(whw, wbf, cur, wxw, wxb, whb, bias2);
    attn_main_kernel<<<BB * NCHUNK, 256, 0, stream>>>(hist, wbf, bias2, vw, partials);
    attn_combine_kernel<<<BB, HIDD, 0, stream>>>(cur, partials, out);
}